// Round 11
// baseline (166.597 us; speedup 1.0000x reference)
//
#include <hip/hip_runtime.h>

// (B,N,DIN,DE,NH,DK) = (4,256,128,64,8,16). Inputs f32, output f32.
#define BB   4
#define NN   256
#define DIN  128
#define DE   64
#define NH   8
#define DK   16
#define CC   128   // NH*DK

typedef __attribute__((ext_vector_type(8))) short short8;   // 8 bf16 = 4 VGPRs
typedef __attribute__((ext_vector_type(4))) float f32x4;

// f32 -> bf16 bits, round-to-nearest-even (round-4-verified numerics)
__device__ __forceinline__ unsigned short f2bfu(float f) {
    union { float f; unsigned int i; } v; v.f = f;
    unsigned int x = v.i;
    x += 0x7FFFu + ((x >> 16) & 1u);
    return (unsigned short)(x >> 16);
}

// ---------------------------------------------------------------------------
// prep: blocks [0,256) do QKV (4 rows per block, verified structure);
//       blocks [256,264) do the one-time WE/WE2 f32->bf16 B-fragment prep.
// wfrag[((m*8+g)*2+ks)*64 + lane] = short8 { W[ks*32+q4*8+ii][g*16+l15] }
// ---------------------------------------------------------------------------
__global__ __launch_bounds__(256) void prep_kernel(
    const float* __restrict__ h, const float* __restrict__ WQ,
    const float* __restrict__ WK, const float* __restrict__ WV,
    const float* __restrict__ WE, const float* __restrict__ WE2,
    float* __restrict__ Qw, float* __restrict__ Kw, float* __restrict__ Vw,
    unsigned short* __restrict__ wfrag)
{
    __shared__ float hsh[4 * DIN];       // 2 KB
    __shared__ float psum[4 * 1536];     // 24 KB
    const int t = threadIdx.x;

    if (blockIdx.x >= 256) {
        // ---- W-frag prep (8 blocks x 256 thr = 2048 threads) ----
        const int tid  = (blockIdx.x - 256) * 256 + t;
        const int m    = tid >> 10;
        const int g    = (tid >> 7) & 7;
        const int ks   = (tid >> 6) & 1;
        const int lane = tid & 63;
        const int q4 = lane >> 4, l15 = lane & 15;
        const float* W = m ? WE2 : WE;
        union { uint4 u; unsigned short s[8]; } pk;
        #pragma unroll
        for (int ii = 0; ii < 8; ++ii) {
            const int d = ks * 32 + q4 * 8 + ii;
            pk.s[ii] = f2bfu(W[d * CC + g * 16 + l15]);
        }
        ((uint4*)wfrag)[tid] = pk.u;
        return;
    }

    // ---- QKV: 4 rows per block ----
    const int r0 = blockIdx.x * 4;
    hsh[t]       = h[(size_t)r0 * DIN + t];
    hsh[256 + t] = h[(size_t)r0 * DIN + 256 + t];
    __syncthreads();

    const int cp  = t & 63;              // channel pair: c = 2cp, 2cp+1
    const int qtr = t >> 6;              // d in [qtr*32, qtr*32+32)
    float aq[4][2], ak[4][2], av[4][2];
    #pragma unroll
    for (int r = 0; r < 4; ++r) {
        aq[r][0]=aq[r][1]=ak[r][0]=ak[r][1]=av[r][0]=av[r][1]=0.f;
    }
    #pragma unroll 4
    for (int dd = 0; dd < 32; ++dd) {
        const int d = qtr * 32 + dd;
        const float2 fq = ((const float2*)WQ)[d * 64 + cp];
        const float2 fk = ((const float2*)WK)[d * 64 + cp];
        const float2 fv = ((const float2*)WV)[d * 64 + cp];
        #pragma unroll
        for (int r = 0; r < 4; ++r) {
            const float hd = hsh[r * DIN + d];
            aq[r][0] = fmaf(hd, fq.x, aq[r][0]); aq[r][1] = fmaf(hd, fq.y, aq[r][1]);
            ak[r][0] = fmaf(hd, fk.x, ak[r][0]); ak[r][1] = fmaf(hd, fk.y, ak[r][1]);
            av[r][0] = fmaf(hd, fv.x, av[r][0]); av[r][1] = fmaf(hd, fv.y, av[r][1]);
        }
    }
    float* pq = psum + qtr * 1536;
    #pragma unroll
    for (int r = 0; r < 4; ++r) {
        pq[r*384       + 2*cp] = aq[r][0]; pq[r*384       + 2*cp+1] = aq[r][1];
        pq[r*384 + 128 + 2*cp] = ak[r][0]; pq[r*384 + 128 + 2*cp+1] = ak[r][1];
        pq[r*384 + 256 + 2*cp] = av[r][0]; pq[r*384 + 256 + 2*cp+1] = av[r][1];
    }
    __syncthreads();
    #pragma unroll
    for (int k = 0; k < 6; ++k) {
        const int o = k * 256 + t;               // 0..1535
        float v = psum[o] + psum[1536 + o] + psum[3072 + o] + psum[4608 + o];
        const int r   = o / 384;
        const int mc  = o - r * 384;
        const int mat = mc >> 7;
        const int c   = mc & 127;
        const size_t idx = (size_t)(r0 + r) * CC + c;
        if      (mat == 0) Qw[idx] = v;
        else if (mat == 1) Kw[idx] = v * 0.25f;  // DK^-0.5
        else               Vw[idx] = v;
    }
}

// ---------------------------------------------------------------------------
// Fused attention, 2 QUERY-ROWS PER BLOCK. ROUND-10 POST-MORTEM: per-block
// critical path ~20us x 2 sequential generations (1024 blocks, 2/CU) = 40us.
// All intra-block scheduling levers were null; the structural fix is ONE
// generation: 512 blocks (2 rows each), all resident at 2 blocks/CU.
// K-reads / V-registers (V depends only on b!) / masks / bfrags amortize 2x.
// e streams through ONE 32KB LDS buffer in j-halves (j 0..127, 128..255);
// half-1 e global loads are register-prefetched under half-0 qk+compute.
// Per-output-element FP order identical to round 10 -> same absmax.
//
// MFMA 16x16x32 bf16 layouts (HW-verified):
//   A: lane holds A[m=lane&15][k=(lane>>4)*8+ii]
//   B: lane holds B[k=(lane>>4)*8+ii][n=lane&15]
//   C/D: col=lane&15, row=(lane>>4)*4+reg
// ---------------------------------------------------------------------------
__global__ __launch_bounds__(512, 4) void attn_kernel(
    const float* __restrict__ e, const float* __restrict__ maskp,
    const unsigned short* __restrict__ wfrag,
    const float* __restrict__ Qw, const float* __restrict__ Kw,
    const float* __restrict__ Vw, float* __restrict__ out)
{
    __shared__ __align__(16) unsigned short esh[2][128 * DE]; // 32 KB: [row][j-half]
    __shared__ float qk_sh[2][128 * 9];                       // 9 KB (current half)
    __shared__ float msk1_sh[2][NN];                          // mi_r*mask[j]
    __shared__ float msk2_sh[2][NN];                          // squared
    __shared__ __align__(16) float qrow_sh[2][CC];            // 1 KB

    const int blk  = blockIdx.x;          // 512 blocks
    const int b    = blk >> 7;            // batch
    const int i0   = (blk & 127) * 2;     // first of this block's 2 rows
    const int t    = threadIdx.x;
    const int wave = t >> 6, lane = t & 63;
    const int q4   = lane >> 4;
    const int l15  = lane & 15;
    const int g    = wave;                // one head per wave

    const int tr = t >> 8;                // staging: row 0/1
    const int tt = t & 255;

    // e row base (float4 units); full row = 4096 float4, half h at h*2048
    const f32x4* erow = (const f32x4*)(e + (size_t)(b * NN + i0 + tr) * NN * DE);
    uint4* eshv = (uint4*)esh;            // [2][1024]

    // ---- issue half-0 e loads (4 pairs/thread = 32 regs) ----
    f32x4 pf[4][2];
    #pragma unroll
    for (int it = 0; it < 4; ++it) {
        const int pp = it * 256 + tt;                    // pair in [0,1024)
        pf[it][0] = __builtin_nontemporal_load(&erow[2 * pp]);
        pf[it][1] = __builtin_nontemporal_load(&erow[2 * pp + 1]);
    }

    // ---- setup while loads fly ----
    if (t < NN) {
        const float mj  = maskp[b * NN + t];
        const float mi0 = maskp[b * NN + i0];
        const float mi1 = maskp[b * NN + i0 + 1];
        const float a0 = mi0 * mj, a1 = mi1 * mj;
        msk1_sh[0][t] = a0;  msk2_sh[0][t] = a0 * a0;
        msk1_sh[1][t] = a1;  msk2_sh[1][t] = a1 * a1;
    }
    if (t < 256) {
        qrow_sh[t >> 7][t & 127] = Qw[(size_t)(b * NN + i0 + (t >> 7)) * CC + (t & 127)];
    }
    short8 bfragE[2], bfragS[2];
    {
        const uint4* wf = (const uint4*)wfrag;
        #pragma unroll
        for (int ks = 0; ks < 2; ++ks) {
            union { uint4 u; short8 s8; } cv;
            cv.u = wf[((0 * 8 + wave) * 2 + ks) * 64 + lane];   // WE
            bfragE[ks] = cv.s8;
            cv.u = wf[((1 * 8 + wave) * 2 + ks) * 64 + lane];   // WE2
            bfragS[ks] = cv.s8;
        }
    }

    // ---- convert + write half 0 (waits only these loads) ----
#define EWRITE() {                                                             \
        _Pragma("unroll")                                                      \
        for (int it = 0; it < 4; ++it) {                                       \
            const int pp = it * 256 + tt;                                      \
            const int jl = pp >> 3, ch8 = pp & 7;                              \
            union { uint4 u; unsigned short s[8]; } pk;                        \
            pk.s[0]=f2bfu(pf[it][0][0]); pk.s[1]=f2bfu(pf[it][0][1]);          \
            pk.s[2]=f2bfu(pf[it][0][2]); pk.s[3]=f2bfu(pf[it][0][3]);          \
            pk.s[4]=f2bfu(pf[it][1][0]); pk.s[5]=f2bfu(pf[it][1][1]);          \
            pk.s[6]=f2bfu(pf[it][1][2]); pk.s[7]=f2bfu(pf[it][1][3]);          \
            eshv[tr * 1024 + jl * 8 + (ch8 ^ (jl & 7))] = pk.u;                \
        } }
    EWRITE();
    __syncthreads();   // esh half0 + qrow + masks visible

    // ---- issue half-1 e prefetch (regs free again) ----
    #pragma unroll
    for (int it = 0; it < 4; ++it) {
        const int pp = it * 256 + tt;
        pf[it][0] = __builtin_nontemporal_load(&erow[2048 + 2 * pp]);
        pf[it][1] = __builtin_nontemporal_load(&erow[2048 + 2 * pp + 1]);
    }
    __builtin_amdgcn_sched_barrier(0);

    // ---- qk + V-hoist helpers ----
    const float* vbase = Vw + ((size_t)(b * NN) + q4 * 4) * CC + g * 16 + l15;
    float vr[8][4];

#define QK_HALF(H) {                                                           \
        const int q = t & 31;                                                  \
        const int hq = q >> 2;                                                 \
        const float4 qv0 = ((const float4*)qrow_sh[0])[q];                     \
        const float4 qv1 = ((const float4*)qrow_sh[1])[q];                     \
        const float4* kb = (const float4*)(Kw + (size_t)(b * NN + (H)*128) * CC); \
        _Pragma("unroll 4")                                                    \
        for (int it = 0; it < 8; ++it) {                                       \
            const int c = it * 512 + t;                                        \
            const int jl = c >> 5;                                             \
            const float4 kv = kb[c];                                           \
            float p0 = kv.x*qv0.x + kv.y*qv0.y + kv.z*qv0.z + kv.w*qv0.w;      \
            float p1 = kv.x*qv1.x + kv.y*qv1.y + kv.z*qv1.z + kv.w*qv1.w;      \
            p0 += __shfl_xor(p0, 1); p0 += __shfl_xor(p0, 2);                  \
            p1 += __shfl_xor(p1, 1); p1 += __shfl_xor(p1, 2);                  \
            if ((t & 3) == 0) {                                                \
                qk_sh[0][jl * 9 + hq] = p0;                                    \
                qk_sh[1][jl * 9 + hq] = p1;                                    \
            }                                                                  \
        } }

#define VHOIST(H) {                                                            \
        _Pragma("unroll")                                                      \
        for (int s = 0; s < 8; ++s)                                            \
            _Pragma("unroll")                                                  \
            for (int r = 0; r < 4; ++r)                                        \
                vr[s][r] = vbase[((H)*128 + s * 16 + r) * CC];                 \
        }

    QK_HALF(0); VHOIST(0);
    __builtin_amdgcn_sched_barrier(0);
    __syncthreads();   // qk_sh half0 ready

    float acc[2] = {0.f, 0.f}, dnm[2] = {0.f, 0.f};
    const short8* ep = (const short8*)esh;   // [2][1024]

#define COMPUTE_HALF(H) {                                                      \
        _Pragma("unroll")                                                      \
        for (int s = 0; s < 8; ++s) {                                          \
            const int ja = s * 16 + l15;                                       \
            _Pragma("unroll")                                                  \
            for (int ri = 0; ri < 2; ++ri) {                                   \
                const short8 a0 = ep[ri*1024 + ja*8 + ((q4    ) ^ (ja & 7))];  \
                const short8 a1 = ep[ri*1024 + ja*8 + ((q4 + 4) ^ (ja & 7))];  \
                f32x4 s2 = {0.f,0.f,0.f,0.f}, eE = {0.f,0.f,0.f,0.f};          \
                s2 = __builtin_amdgcn_mfma_f32_16x16x32_bf16(a0, bfragS[0], s2, 0,0,0); \
                s2 = __builtin_amdgcn_mfma_f32_16x16x32_bf16(a1, bfragS[1], s2, 0,0,0); \
                eE = __builtin_amdgcn_mfma_f32_16x16x32_bf16(a0, bfragE[0], eE, 0,0,0); \
                eE = __builtin_amdgcn_mfma_f32_16x16x32_bf16(a1, bfragE[1], eE, 0,0,0); \
                _Pragma("unroll")                                              \
                for (int rq = 0; rq < 4; ++rq) {                               \
                    const int jl = s * 16 + q4 * 4 + rq;                       \
                    const int jg = (H) * 128 + jl;                             \
                    float sc = qk_sh[ri][jl * 9 + g] + s2[rq];                 \
                    sc = fminf(5.f, fmaxf(-5.f, sc));                          \
                    const float p = __expf(sc);                                \
                    dnm[ri] = fmaf(p, msk1_sh[ri][jg], dnm[ri]);               \
                    acc[ri] = fmaf(p * msk2_sh[ri][jg], vr[s][rq] + eE[rq], acc[ri]); \
                }                                                              \
            }                                                                  \
        } }

    COMPUTE_HALF(0);
    __syncthreads();   // all half-0 esh/qk_sh reads done before overwrite

    // ---- convert + write half 1 (vmcnt wait on prefetch inserted here) ----
    EWRITE();
    __syncthreads();   // esh half1 visible

    QK_HALF(1); VHOIST(1);
    __builtin_amdgcn_sched_barrier(0);
    __syncthreads();   // qk_sh half1 ready

    COMPUTE_HALF(1);

#undef COMPUTE_HALF
#undef VHOIST
#undef QK_HALF
#undef EWRITE

    // reduce over quad groups (lanes l, l^16, l^32, l^48 share a column)
    #pragma unroll
    for (int ri = 0; ri < 2; ++ri) {
        float a = acc[ri], d = dnm[ri];
        a += __shfl_xor(a, 16); a += __shfl_xor(a, 32);
        d += __shfl_xor(d, 16); d += __shfl_xor(d, 32);
        if (lane < 16) {
            out[(size_t)(b * NN + i0 + ri) * CC + g * 16 + lane] =
                a / fmaxf(d, 1e-6f);
        }
    }
}

extern "C" void kernel_launch(void* const* d_in, const int* in_sizes, int n_in,
                              void* d_out, int out_size, void* d_ws, size_t ws_size,
                              hipStream_t stream)
{
    const float* h    = (const float*)d_in[0];
    const float* e    = (const float*)d_in[1];
    const float* mask = (const float*)d_in[2];
    const float* WQ   = (const float*)d_in[3];
    const float* WK   = (const float*)d_in[4];
    const float* WV   = (const float*)d_in[5];
    const float* WE   = (const float*)d_in[6];
    const float* WE2  = (const float*)d_in[7];

    unsigned short* wfrag = (unsigned short*)d_ws;          // 32 KB
    float* Qw = (float*)((char*)d_ws + 32768);              // B*N*C f32 each
    float* Kw = Qw + BB * NN * CC;
    float* Vw = Kw + BB * NN * CC;                          // total ~1.53 MB

    prep_kernel<<<264, 256, 0, stream>>>(h, WQ, WK, WV, WE, WE2,
                                         Qw, Kw, Vw, wfrag);
    attn_kernel<<<BB*NN/2, 512, 0, stream>>>(e, mask, wfrag, Qw, Kw, Vw,
                                             (float*)d_out);
}

// Round 12
// 161.458 us; speedup vs baseline: 1.0318x; 1.0318x over previous
//
#include <hip/hip_runtime.h>

// (B,N,DIN,DE,NH,DK) = (4,256,128,64,8,16). Inputs f32, output f32.
#define BB   4
#define NN   256
#define DIN  128
#define DE   64
#define NH   8
#define DK   16
#define CC   128   // NH*DK

typedef __attribute__((ext_vector_type(8))) short short8;   // 8 bf16 = 4 VGPRs
typedef __attribute__((ext_vector_type(4))) float f32x4;

// f32 -> bf16 bits, round-to-nearest-even (round-4-verified numerics)
__device__ __forceinline__ unsigned short f2bfu(float f) {
    union { float f; unsigned int i; } v; v.f = f;
    unsigned int x = v.i;
    x += 0x7FFFu + ((x >> 16) & 1u);
    return (unsigned short)(x >> 16);
}

// ---------------------------------------------------------------------------
// prep: blocks [0,256) do QKV (4 rows per block, verified structure);
//       blocks [256,264) do the one-time WE/WE2 f32->bf16 B-fragment prep.
// wfrag[((m*8+g)*2+ks)*64 + lane] = short8 { W[ks*32+q4*8+ii][g*16+l15] }
// ---------------------------------------------------------------------------
__global__ __launch_bounds__(256) void prep_kernel(
    const float* __restrict__ h, const float* __restrict__ WQ,
    const float* __restrict__ WK, const float* __restrict__ WV,
    const float* __restrict__ WE, const float* __restrict__ WE2,
    float* __restrict__ Qw, float* __restrict__ Kw, float* __restrict__ Vw,
    unsigned short* __restrict__ wfrag)
{
    __shared__ float hsh[4 * DIN];       // 2 KB
    __shared__ float psum[4 * 1536];     // 24 KB
    const int t = threadIdx.x;

    if (blockIdx.x >= 256) {
        // ---- W-frag prep (8 blocks x 256 thr = 2048 threads) ----
        const int tid  = (blockIdx.x - 256) * 256 + t;
        const int m    = tid >> 10;
        const int g    = (tid >> 7) & 7;
        const int ks   = (tid >> 6) & 1;
        const int lane = tid & 63;
        const int q4 = lane >> 4, l15 = lane & 15;
        const float* W = m ? WE2 : WE;
        union { uint4 u; unsigned short s[8]; } pk;
        #pragma unroll
        for (int ii = 0; ii < 8; ++ii) {
            const int d = ks * 32 + q4 * 8 + ii;
            pk.s[ii] = f2bfu(W[d * CC + g * 16 + l15]);
        }
        ((uint4*)wfrag)[tid] = pk.u;
        return;
    }

    // ---- QKV: 4 rows per block ----
    const int r0 = blockIdx.x * 4;
    hsh[t]       = h[(size_t)r0 * DIN + t];
    hsh[256 + t] = h[(size_t)r0 * DIN + 256 + t];
    __syncthreads();

    const int cp  = t & 63;              // channel pair: c = 2cp, 2cp+1
    const int qtr = t >> 6;              // d in [qtr*32, qtr*32+32)
    float aq[4][2], ak[4][2], av[4][2];
    #pragma unroll
    for (int r = 0; r < 4; ++r) {
        aq[r][0]=aq[r][1]=ak[r][0]=ak[r][1]=av[r][0]=av[r][1]=0.f;
    }
    #pragma unroll 4
    for (int dd = 0; dd < 32; ++dd) {
        const int d = qtr * 32 + dd;
        const float2 fq = ((const float2*)WQ)[d * 64 + cp];
        const float2 fk = ((const float2*)WK)[d * 64 + cp];
        const float2 fv = ((const float2*)WV)[d * 64 + cp];
        #pragma unroll
        for (int r = 0; r < 4; ++r) {
            const float hd = hsh[r * DIN + d];
            aq[r][0] = fmaf(hd, fq.x, aq[r][0]); aq[r][1] = fmaf(hd, fq.y, aq[r][1]);
            ak[r][0] = fmaf(hd, fk.x, ak[r][0]); ak[r][1] = fmaf(hd, fk.y, ak[r][1]);
            av[r][0] = fmaf(hd, fv.x, av[r][0]); av[r][1] = fmaf(hd, fv.y, av[r][1]);
        }
    }
    float* pq = psum + qtr * 1536;
    #pragma unroll
    for (int r = 0; r < 4; ++r) {
        pq[r*384       + 2*cp] = aq[r][0]; pq[r*384       + 2*cp+1] = aq[r][1];
        pq[r*384 + 128 + 2*cp] = ak[r][0]; pq[r*384 + 128 + 2*cp+1] = ak[r][1];
        pq[r*384 + 256 + 2*cp] = av[r][0]; pq[r*384 + 256 + 2*cp+1] = av[r][1];
    }
    __syncthreads();
    #pragma unroll
    for (int k = 0; k < 6; ++k) {
        const int o = k * 256 + t;               // 0..1535
        float v = psum[o] + psum[1536 + o] + psum[3072 + o] + psum[4608 + o];
        const int r   = o / 384;
        const int mc  = o - r * 384;
        const int mat = mc >> 7;
        const int c   = mc & 127;
        const size_t idx = (size_t)(r0 + r) * CC + c;
        if      (mat == 0) Qw[idx] = v;
        else if (mat == 1) Kw[idx] = v * 0.25f;  // DK^-0.5
        else               Vw[idx] = v;
    }
}

// ---------------------------------------------------------------------------
// Fused attention, 2 QUERY-ROWS PER BLOCK (one generation: 512 blocks at
// 2/CU). ROUND-11 POST-MORTEM: pf[4][2] e-prefetch held 32 VGPR across the
// qk+vhoist region -> over the 128 cap -> 64-VGPR pin + 98MB scratch. THIS
// version needs NO register prefetch: dropping msk2 (m1*m1 inline, FP-
// identical) and reusing qk_sh per j-half lets the FULL e for both rows fit
// LDS (64K esh + 9.2K qk + 2K msk + 1K qrow = 76K <= 80K). One up-front
// stage (BW-bound, pipelined), then per j-half: qk -> compute. Phases are
// register-disjoint: stage ~64 transient, qk ~30, compute vr(32)+bfrag(16).
// Go/no-go: WRITE_SIZE ~1MB (balloon = reg-infeasible -> revert to r10).
//
// MFMA 16x16x32 bf16 layouts (HW-verified):
//   A: lane holds A[m=lane&15][k=(lane>>4)*8+ii]
//   B: lane holds B[k=(lane>>4)*8+ii][n=lane&15]
//   C/D: col=lane&15, row=(lane>>4)*4+reg
// ---------------------------------------------------------------------------
__global__ __launch_bounds__(512, 4) void attn_kernel(
    const float* __restrict__ e, const float* __restrict__ maskp,
    const unsigned short* __restrict__ wfrag,
    const float* __restrict__ Qw, const float* __restrict__ Kw,
    const float* __restrict__ Vw, float* __restrict__ out)
{
    __shared__ __align__(16) unsigned short esh[2][NN * DE];  // 64 KB: both rows, full j
    __shared__ float qk_sh[2][128 * 9];                       // 9.2 KB, per-half reuse
    __shared__ float msk1_sh[2][NN];                          // 2 KB: mi_r * mask[j]
    __shared__ __align__(16) float qrow_sh[2][CC];            // 1 KB

    const int blk  = blockIdx.x;          // 512 blocks
    const int b    = blk >> 7;            // batch
    const int i0   = (blk & 127) * 2;     // this block's 2 query rows
    const int t    = threadIdx.x;
    const int wave = t >> 6, lane = t & 63;
    const int q4   = lane >> 4;
    const int l15  = lane & 15;
    const int g    = wave;                // one head per wave

    // ---- stage ALL e for both rows: 4096 16B chunks, 8 per thread ----
    {
        uint4* eshv = (uint4*)esh;
        const f32x4* er0 = (const f32x4*)(e + (size_t)(b * NN + i0)     * NN * DE);
        const f32x4* er1 = (const f32x4*)(e + (size_t)(b * NN + i0 + 1) * NN * DE);
        #pragma unroll
        for (int it = 0; it < 4; ++it) {
            const int pp = it * 512 + t;            // chunk 0..2047 (row 0)
            const int jg = pp >> 3, ch = pp & 7;
            const f32x4 f0 = __builtin_nontemporal_load(&er0[2 * pp]);
            const f32x4 f1 = __builtin_nontemporal_load(&er0[2 * pp + 1]);
            union { uint4 u; unsigned short s[8]; } pk;
            pk.s[0]=f2bfu(f0[0]); pk.s[1]=f2bfu(f0[1]); pk.s[2]=f2bfu(f0[2]); pk.s[3]=f2bfu(f0[3]);
            pk.s[4]=f2bfu(f1[0]); pk.s[5]=f2bfu(f1[1]); pk.s[6]=f2bfu(f1[2]); pk.s[7]=f2bfu(f1[3]);
            eshv[jg * 8 + (ch ^ (jg & 7))] = pk.u;
        }
        #pragma unroll
        for (int it = 0; it < 4; ++it) {
            const int pp = it * 512 + t;            // chunk 0..2047 (row 1)
            const int jg = pp >> 3, ch = pp & 7;
            const f32x4 f0 = __builtin_nontemporal_load(&er1[2 * pp]);
            const f32x4 f1 = __builtin_nontemporal_load(&er1[2 * pp + 1]);
            union { uint4 u; unsigned short s[8]; } pk;
            pk.s[0]=f2bfu(f0[0]); pk.s[1]=f2bfu(f0[1]); pk.s[2]=f2bfu(f0[2]); pk.s[3]=f2bfu(f0[3]);
            pk.s[4]=f2bfu(f1[0]); pk.s[5]=f2bfu(f1[1]); pk.s[6]=f2bfu(f1[2]); pk.s[7]=f2bfu(f1[3]);
            eshv[2048 + jg * 8 + (ch ^ (jg & 7))] = pk.u;
        }
    }

    // ---- setup while stage loads fly ----
    if (t < NN) {
        const float mj  = maskp[b * NN + t];
        const float mi0 = maskp[b * NN + i0];
        const float mi1 = maskp[b * NN + i0 + 1];
        msk1_sh[0][t] = mi0 * mj;
        msk1_sh[1][t] = mi1 * mj;
    }
    if (t < 256) {
        qrow_sh[t >> 7][t & 127] =
            Qw[(size_t)(b * NN + i0 + (t >> 7)) * CC + (t & 127)];
    }
    short8 bfragE[2], bfragS[2];
    {
        const uint4* wf = (const uint4*)wfrag;
        #pragma unroll
        for (int ks = 0; ks < 2; ++ks) {
            union { uint4 u; short8 s8; } cv;
            cv.u = wf[((0 * 8 + wave) * 2 + ks) * 64 + lane];   // WE
            bfragE[ks] = cv.s8;
            cv.u = wf[((1 * 8 + wave) * 2 + ks) * 64 + lane];   // WE2
            bfragS[ks] = cv.s8;
        }
    }
    __syncthreads();   // esh, masks, qrow visible

    const float* vbase = Vw + ((size_t)(b * NN) + q4 * 4) * CC + g * 16 + l15;
    float vr[8][4];
    float acc[2] = {0.f, 0.f}, dnm[2] = {0.f, 0.f};
    const short8* ep = (const short8*)esh;   // [2][2048]

    // qk for rows H*128..H*128+127 (coalesced, round-9-verified pattern)
#define QK_HALF(H) {                                                           \
        const int q = t & 31;                                                  \
        const int hq = q >> 2;                                                 \
        const float4 qv0 = ((const float4*)qrow_sh[0])[q];                     \
        const float4 qv1 = ((const float4*)qrow_sh[1])[q];                     \
        const float4* kb = (const float4*)(Kw + (size_t)(b * NN + (H)*128) * CC); \
        _Pragma("unroll 4")                                                    \
        for (int it = 0; it < 8; ++it) {                                       \
            const int c = it * 512 + t;                                        \
            const int jl = c >> 5;                                             \
            const float4 kv = kb[c];                                           \
            float p0 = kv.x*qv0.x + kv.y*qv0.y + kv.z*qv0.z + kv.w*qv0.w;      \
            float p1 = kv.x*qv1.x + kv.y*qv1.y + kv.z*qv1.z + kv.w*qv1.w;      \
            p0 += __shfl_xor(p0, 1); p0 += __shfl_xor(p0, 2);                  \
            p1 += __shfl_xor(p1, 1); p1 += __shfl_xor(p1, 2);                  \
            if ((t & 3) == 0) {                                                \
                qk_sh[0][jl * 9 + hq] = p0;                                    \
                qk_sh[1][jl * 9 + hq] = p1;                                    \
            }                                                                  \
        } }

#define VHOIST(H) {                                                            \
        _Pragma("unroll")                                                      \
        for (int s = 0; s < 8; ++s)                                            \
            _Pragma("unroll")                                                  \
            for (int r = 0; r < 4; ++r)                                        \
                vr[s][r] = vbase[((H)*128 + s * 16 + r) * CC];                 \
        }

#define COMPUTE_HALF(H) {                                                      \
        _Pragma("unroll")                                                      \
        for (int s = 0; s < 8; ++s) {                                          \
            const int jga = (H) * 128 + s * 16 + l15;   /* global A-row */     \
            _Pragma("unroll")                                                  \
            for (int ri = 0; ri < 2; ++ri) {                                   \
                const short8 a0 = ep[ri*2048 + jga*8 + ((q4    ) ^ (jga & 7))];\
                const short8 a1 = ep[ri*2048 + jga*8 + ((q4 + 4) ^ (jga & 7))];\
                f32x4 s2 = {0.f,0.f,0.f,0.f}, eE = {0.f,0.f,0.f,0.f};          \
                s2 = __builtin_amdgcn_mfma_f32_16x16x32_bf16(a0, bfragS[0], s2, 0,0,0); \
                s2 = __builtin_amdgcn_mfma_f32_16x16x32_bf16(a1, bfragS[1], s2, 0,0,0); \
                eE = __builtin_amdgcn_mfma_f32_16x16x32_bf16(a0, bfragE[0], eE, 0,0,0); \
                eE = __builtin_amdgcn_mfma_f32_16x16x32_bf16(a1, bfragE[1], eE, 0,0,0); \
                _Pragma("unroll")                                              \
                for (int rq = 0; rq < 4; ++rq) {                               \
                    const int jl = s * 16 + q4 * 4 + rq;                       \
                    const int jg = (H) * 128 + jl;                             \
                    float sc = qk_sh[ri][jl * 9 + g] + s2[rq];                 \
                    sc = fminf(5.f, fmaxf(-5.f, sc));                          \
                    const float p = __expf(sc);                                \
                    const float m1 = msk1_sh[ri][jg];                          \
                    dnm[ri] = fmaf(p, m1, dnm[ri]);                            \
                    acc[ri] = fmaf(p * (m1 * m1), vr[s][rq] + eE[rq], acc[ri]);\
                }                                                              \
            }                                                                  \
        } }

    QK_HALF(0); VHOIST(0);
    __builtin_amdgcn_sched_barrier(0);
    __syncthreads();   // qk_sh half-0 ready
    COMPUTE_HALF(0);
    __syncthreads();   // qk_sh half-0 reads done before overwrite

    QK_HALF(1); VHOIST(1);
    __builtin_amdgcn_sched_barrier(0);
    __syncthreads();   // qk_sh half-1 ready
    COMPUTE_HALF(1);

#undef COMPUTE_HALF
#undef VHOIST
#undef QK_HALF

    // reduce over quad groups (lanes l, l^16, l^32, l^48 share a column)
    #pragma unroll
    for (int ri = 0; ri < 2; ++ri) {
        float a = acc[ri], d = dnm[ri];
        a += __shfl_xor(a, 16); a += __shfl_xor(a, 32);
        d += __shfl_xor(d, 16); d += __shfl_xor(d, 32);
        if (lane < 16) {
            out[(size_t)(b * NN + i0 + ri) * CC + g * 16 + lane] =
                a / fmaxf(d, 1e-6f);
        }
    }
}

extern "C" void kernel_launch(void* const* d_in, const int* in_sizes, int n_in,
                              void* d_out, int out_size, void* d_ws, size_t ws_size,
                              hipStream_t stream)
{
    const float* h    = (const float*)d_in[0];
    const float* e    = (const float*)d_in[1];
    const float* mask = (const float*)d_in[2];
    const float* WQ   = (const float*)d_in[3];
    const float* WK   = (const float*)d_in[4];
    const float* WV   = (const float*)d_in[5];
    const float* WE   = (const float*)d_in[6];
    const float* WE2  = (const float*)d_in[7];

    unsigned short* wfrag = (unsigned short*)d_ws;          // 32 KB
    float* Qw = (float*)((char*)d_ws + 32768);              // B*N*C f32 each
    float* Kw = Qw + BB * NN * CC;
    float* Vw = Kw + BB * NN * CC;                          // total ~1.53 MB

    prep_kernel<<<264, 256, 0, stream>>>(h, WQ, WK, WV, WE, WE2,
                                         Qw, Kw, Vw, wfrag);
    attn_kernel<<<BB*NN/2, 512, 0, stream>>>(e, mask, wfrag, Qw, Kw, Vw,
                                             (float*)d_out);
}

// Round 13
// 148.420 us; speedup vs baseline: 1.1225x; 1.0878x over previous
//
#include <hip/hip_runtime.h>

// (B,N,DIN,DE,NH,DK) = (4,256,128,64,8,16). Inputs f32, output f32.
#define BB   4
#define NN   256
#define DIN  128
#define DE   64
#define NH   8
#define DK   16
#define CC   128   // NH*DK

typedef __attribute__((ext_vector_type(8))) short short8;   // 8 bf16 = 4 VGPRs
typedef __attribute__((ext_vector_type(4))) float f32x4;

// f32 -> bf16 bits, round-to-nearest-even (round-4-verified numerics)
__device__ __forceinline__ unsigned short f2bfu(float f) {
    union { float f; unsigned int i; } v; v.f = f;
    unsigned int x = v.i;
    x += 0x7FFFu + ((x >> 16) & 1u);
    return (unsigned short)(x >> 16);
}

// ---------------------------------------------------------------------------
// prep: blocks [0,256) do QKV (4 rows per block, verified structure);
//       blocks [256,264) do the one-time WE/WE2 f32->bf16 B-fragment prep.
// wfrag[((m*8+g)*2+ks)*64 + lane] = short8 { W[ks*32+q4*8+ii][g*16+l15] }
// ---------------------------------------------------------------------------
__global__ __launch_bounds__(256) void prep_kernel(
    const float* __restrict__ h, const float* __restrict__ WQ,
    const float* __restrict__ WK, const float* __restrict__ WV,
    const float* __restrict__ WE, const float* __restrict__ WE2,
    float* __restrict__ Qw, float* __restrict__ Kw, float* __restrict__ Vw,
    unsigned short* __restrict__ wfrag)
{
    __shared__ float hsh[4 * DIN];       // 2 KB
    __shared__ float psum[4 * 1536];     // 24 KB
    const int t = threadIdx.x;

    if (blockIdx.x >= 256) {
        // ---- W-frag prep (8 blocks x 256 thr = 2048 threads) ----
        const int tid  = (blockIdx.x - 256) * 256 + t;
        const int m    = tid >> 10;
        const int g    = (tid >> 7) & 7;
        const int ks   = (tid >> 6) & 1;
        const int lane = tid & 63;
        const int q4 = lane >> 4, l15 = lane & 15;
        const float* W = m ? WE2 : WE;
        union { uint4 u; unsigned short s[8]; } pk;
        #pragma unroll
        for (int ii = 0; ii < 8; ++ii) {
            const int d = ks * 32 + q4 * 8 + ii;
            pk.s[ii] = f2bfu(W[d * CC + g * 16 + l15]);
        }
        ((uint4*)wfrag)[tid] = pk.u;
        return;
    }

    // ---- QKV: 4 rows per block ----
    const int r0 = blockIdx.x * 4;
    hsh[t]       = h[(size_t)r0 * DIN + t];
    hsh[256 + t] = h[(size_t)r0 * DIN + 256 + t];
    __syncthreads();

    const int cp  = t & 63;              // channel pair: c = 2cp, 2cp+1
    const int qtr = t >> 6;              // d in [qtr*32, qtr*32+32)
    float aq[4][2], ak[4][2], av[4][2];
    #pragma unroll
    for (int r = 0; r < 4; ++r) {
        aq[r][0]=aq[r][1]=ak[r][0]=ak[r][1]=av[r][0]=av[r][1]=0.f;
    }
    #pragma unroll 4
    for (int dd = 0; dd < 32; ++dd) {
        const int d = qtr * 32 + dd;
        const float2 fq = ((const float2*)WQ)[d * 64 + cp];
        const float2 fk = ((const float2*)WK)[d * 64 + cp];
        const float2 fv = ((const float2*)WV)[d * 64 + cp];
        #pragma unroll
        for (int r = 0; r < 4; ++r) {
            const float hd = hsh[r * DIN + d];
            aq[r][0] = fmaf(hd, fq.x, aq[r][0]); aq[r][1] = fmaf(hd, fq.y, aq[r][1]);
            ak[r][0] = fmaf(hd, fk.x, ak[r][0]); ak[r][1] = fmaf(hd, fk.y, ak[r][1]);
            av[r][0] = fmaf(hd, fv.x, av[r][0]); av[r][1] = fmaf(hd, fv.y, av[r][1]);
        }
    }
    float* pq = psum + qtr * 1536;
    #pragma unroll
    for (int r = 0; r < 4; ++r) {
        pq[r*384       + 2*cp] = aq[r][0]; pq[r*384       + 2*cp+1] = aq[r][1];
        pq[r*384 + 128 + 2*cp] = ak[r][0]; pq[r*384 + 128 + 2*cp+1] = ak[r][1];
        pq[r*384 + 256 + 2*cp] = av[r][0]; pq[r*384 + 256 + 2*cp+1] = av[r][1];
    }
    __syncthreads();
    #pragma unroll
    for (int k = 0; k < 6; ++k) {
        const int o = k * 256 + t;               // 0..1535
        float v = psum[o] + psum[1536 + o] + psum[3072 + o] + psum[4608 + o];
        const int r   = o / 384;
        const int mc  = o - r * 384;
        const int mat = mc >> 7;
        const int c   = mc & 127;
        const size_t idx = (size_t)(r0 + r) * CC + c;
        if      (mat == 0) Qw[idx] = v;
        else if (mat == 1) Kw[idx] = v * 0.25f;  // DK^-0.5
        else               Vw[idx] = v;
    }
}

// ---------------------------------------------------------------------------
// Fused attention, 2 QUERY-ROWS PER BLOCK (one generation: 512 blocks at
// 2/CU, LDS-bound). ROUND-12 POST-MORTEM: the 64-VGPR pin + spill recurred
// with register-disjoint phases — cross-referencing all rounds, EVERY
// spilled kernel used __launch_bounds__(·,4) (r1,r2,r11,r12) and r3's only
// change (4->3) eliminated the identical spill. Empirically hipcc's handling
// of the 2nd arg triggers a 64-reg pin on register-heavy kernels at 4.
// THIS round is a single-variable A/B vs r12: (512,4) -> (512,2). Occupancy
// is LDS-bound at 2 blocks/CU either way, so the relaxed bound costs nothing.
// Go/no-go: VGPR >= 96 and WRITE_SIZE < 2 MB. Fail -> revert to round-5.
//
// MFMA 16x16x32 bf16 layouts (HW-verified):
//   A: lane holds A[m=lane&15][k=(lane>>4)*8+ii]
//   B: lane holds B[k=(lane>>4)*8+ii][n=lane&15]
//   C/D: col=lane&15, row=(lane>>4)*4+reg
// ---------------------------------------------------------------------------
__global__ __launch_bounds__(512, 2) void attn_kernel(
    const float* __restrict__ e, const float* __restrict__ maskp,
    const unsigned short* __restrict__ wfrag,
    const float* __restrict__ Qw, const float* __restrict__ Kw,
    const float* __restrict__ Vw, float* __restrict__ out)
{
    __shared__ __align__(16) unsigned short esh[2][NN * DE];  // 64 KB: both rows, full j
    __shared__ float qk_sh[2][128 * 9];                       // 9.2 KB, per-half reuse
    __shared__ float msk1_sh[2][NN];                          // 2 KB: mi_r * mask[j]
    __shared__ __align__(16) float qrow_sh[2][CC];            // 1 KB

    const int blk  = blockIdx.x;          // 512 blocks
    const int b    = blk >> 7;            // batch
    const int i0   = (blk & 127) * 2;     // this block's 2 query rows
    const int t    = threadIdx.x;
    const int wave = t >> 6, lane = t & 63;
    const int q4   = lane >> 4;
    const int l15  = lane & 15;
    const int g    = wave;                // one head per wave

    // ---- stage ALL e for both rows: 4096 16B chunks, 8 per thread ----
    {
        uint4* eshv = (uint4*)esh;
        const f32x4* er0 = (const f32x4*)(e + (size_t)(b * NN + i0)     * NN * DE);
        const f32x4* er1 = (const f32x4*)(e + (size_t)(b * NN + i0 + 1) * NN * DE);
        #pragma unroll
        for (int it = 0; it < 4; ++it) {
            const int pp = it * 512 + t;            // chunk 0..2047 (row 0)
            const int jg = pp >> 3, ch = pp & 7;
            const f32x4 f0 = __builtin_nontemporal_load(&er0[2 * pp]);
            const f32x4 f1 = __builtin_nontemporal_load(&er0[2 * pp + 1]);
            union { uint4 u; unsigned short s[8]; } pk;
            pk.s[0]=f2bfu(f0[0]); pk.s[1]=f2bfu(f0[1]); pk.s[2]=f2bfu(f0[2]); pk.s[3]=f2bfu(f0[3]);
            pk.s[4]=f2bfu(f1[0]); pk.s[5]=f2bfu(f1[1]); pk.s[6]=f2bfu(f1[2]); pk.s[7]=f2bfu(f1[3]);
            eshv[jg * 8 + (ch ^ (jg & 7))] = pk.u;
        }
        #pragma unroll
        for (int it = 0; it < 4; ++it) {
            const int pp = it * 512 + t;            // chunk 0..2047 (row 1)
            const int jg = pp >> 3, ch = pp & 7;
            const f32x4 f0 = __builtin_nontemporal_load(&er1[2 * pp]);
            const f32x4 f1 = __builtin_nontemporal_load(&er1[2 * pp + 1]);
            union { uint4 u; unsigned short s[8]; } pk;
            pk.s[0]=f2bfu(f0[0]); pk.s[1]=f2bfu(f0[1]); pk.s[2]=f2bfu(f0[2]); pk.s[3]=f2bfu(f0[3]);
            pk.s[4]=f2bfu(f1[0]); pk.s[5]=f2bfu(f1[1]); pk.s[6]=f2bfu(f1[2]); pk.s[7]=f2bfu(f1[3]);
            eshv[2048 + jg * 8 + (ch ^ (jg & 7))] = pk.u;
        }
    }

    // ---- setup while stage loads fly ----
    if (t < NN) {
        const float mj  = maskp[b * NN + t];
        const float mi0 = maskp[b * NN + i0];
        const float mi1 = maskp[b * NN + i0 + 1];
        msk1_sh[0][t] = mi0 * mj;
        msk1_sh[1][t] = mi1 * mj;
    }
    if (t < 256) {
        qrow_sh[t >> 7][t & 127] =
            Qw[(size_t)(b * NN + i0 + (t >> 7)) * CC + (t & 127)];
    }
    short8 bfragE[2], bfragS[2];
    {
        const uint4* wf = (const uint4*)wfrag;
        #pragma unroll
        for (int ks = 0; ks < 2; ++ks) {
            union { uint4 u; short8 s8; } cv;
            cv.u = wf[((0 * 8 + wave) * 2 + ks) * 64 + lane];   // WE
            bfragE[ks] = cv.s8;
            cv.u = wf[((1 * 8 + wave) * 2 + ks) * 64 + lane];   // WE2
            bfragS[ks] = cv.s8;
        }
    }
    __syncthreads();   // esh, masks, qrow visible

    const float* vbase = Vw + ((size_t)(b * NN) + q4 * 4) * CC + g * 16 + l15;
    float vr[8][4];
    float acc[2] = {0.f, 0.f}, dnm[2] = {0.f, 0.f};
    const short8* ep = (const short8*)esh;   // [2][2048]

    // qk for rows H*128..H*128+127 (coalesced, round-9-verified pattern)
#define QK_HALF(H) {                                                           \
        const int q = t & 31;                                                  \
        const int hq = q >> 2;                                                 \
        const float4 qv0 = ((const float4*)qrow_sh[0])[q];                     \
        const float4 qv1 = ((const float4*)qrow_sh[1])[q];                     \
        const float4* kb = (const float4*)(Kw + (size_t)(b * NN + (H)*128) * CC); \
        _Pragma("unroll 4")                                                    \
        for (int it = 0; it < 8; ++it) {                                       \
            const int c = it * 512 + t;                                        \
            const int jl = c >> 5;                                             \
            const float4 kv = kb[c];                                           \
            float p0 = kv.x*qv0.x + kv.y*qv0.y + kv.z*qv0.z + kv.w*qv0.w;      \
            float p1 = kv.x*qv1.x + kv.y*qv1.y + kv.z*qv1.z + kv.w*qv1.w;      \
            p0 += __shfl_xor(p0, 1); p0 += __shfl_xor(p0, 2);                  \
            p1 += __shfl_xor(p1, 1); p1 += __shfl_xor(p1, 2);                  \
            if ((t & 3) == 0) {                                                \
                qk_sh[0][jl * 9 + hq] = p0;                                    \
                qk_sh[1][jl * 9 + hq] = p1;                                    \
            }                                                                  \
        } }

#define VHOIST(H) {                                                            \
        _Pragma("unroll")                                                      \
        for (int s = 0; s < 8; ++s)                                            \
            _Pragma("unroll")                                                  \
            for (int r = 0; r < 4; ++r)                                        \
                vr[s][r] = vbase[((H)*128 + s * 16 + r) * CC];                 \
        }

#define COMPUTE_HALF(H) {                                                      \
        _Pragma("unroll")                                                      \
        for (int s = 0; s < 8; ++s) {                                          \
            const int jga = (H) * 128 + s * 16 + l15;   /* global A-row */     \
            _Pragma("unroll")                                                  \
            for (int ri = 0; ri < 2; ++ri) {                                   \
                const short8 a0 = ep[ri*2048 + jga*8 + ((q4    ) ^ (jga & 7))];\
                const short8 a1 = ep[ri*2048 + jga*8 + ((q4 + 4) ^ (jga & 7))];\
                f32x4 s2 = {0.f,0.f,0.f,0.f}, eE = {0.f,0.f,0.f,0.f};          \
                s2 = __builtin_amdgcn_mfma_f32_16x16x32_bf16(a0, bfragS[0], s2, 0,0,0); \
                s2 = __builtin_amdgcn_mfma_f32_16x16x32_bf16(a1, bfragS[1], s2, 0,0,0); \
                eE = __builtin_amdgcn_mfma_f32_16x16x32_bf16(a0, bfragE[0], eE, 0,0,0); \
                eE = __builtin_amdgcn_mfma_f32_16x16x32_bf16(a1, bfragE[1], eE, 0,0,0); \
                _Pragma("unroll")                                              \
                for (int rq = 0; rq < 4; ++rq) {                               \
                    const int jl = s * 16 + q4 * 4 + rq;                       \
                    const int jg = (H) * 128 + jl;                             \
                    float sc = qk_sh[ri][jl * 9 + g] + s2[rq];                 \
                    sc = fminf(5.f, fmaxf(-5.f, sc));                          \
                    const float p = __expf(sc);                                \
                    const float m1 = msk1_sh[ri][jg];                          \
                    dnm[ri] = fmaf(p, m1, dnm[ri]);                            \
                    acc[ri] = fmaf(p * (m1 * m1), vr[s][rq] + eE[rq], acc[ri]);\
                }                                                              \
            }                                                                  \
        } }

    QK_HALF(0); VHOIST(0);
    __builtin_amdgcn_sched_barrier(0);
    __syncthreads();   // qk_sh half-0 ready
    COMPUTE_HALF(0);
    __syncthreads();   // qk_sh half-0 reads done before overwrite

    QK_HALF(1); VHOIST(1);
    __builtin_amdgcn_sched_barrier(0);
    __syncthreads();   // qk_sh half-1 ready
    COMPUTE_HALF(1);

#undef COMPUTE_HALF
#undef VHOIST
#undef QK_HALF

    // reduce over quad groups (lanes l, l^16, l^32, l^48 share a column)
    #pragma unroll
    for (int ri = 0; ri < 2; ++ri) {
        float a = acc[ri], d = dnm[ri];
        a += __shfl_xor(a, 16); a += __shfl_xor(a, 32);
        d += __shfl_xor(d, 16); d += __shfl_xor(d, 32);
        if (lane < 16) {
            out[(size_t)(b * NN + i0 + ri) * CC + g * 16 + lane] =
                a / fmaxf(d, 1e-6f);
        }
    }
}

extern "C" void kernel_launch(void* const* d_in, const int* in_sizes, int n_in,
                              void* d_out, int out_size, void* d_ws, size_t ws_size,
                              hipStream_t stream)
{
    const float* h    = (const float*)d_in[0];
    const float* e    = (const float*)d_in[1];
    const float* mask = (const float*)d_in[2];
    const float* WQ   = (const float*)d_in[3];
    const float* WK   = (const float*)d_in[4];
    const float* WV   = (const float*)d_in[5];
    const float* WE   = (const float*)d_in[6];
    const float* WE2  = (const float*)d_in[7];

    unsigned short* wfrag = (unsigned short*)d_ws;          // 32 KB
    float* Qw = (float*)((char*)d_ws + 32768);              // B*N*C f32 each
    float* Kw = Qw + BB * NN * CC;
    float* Vw = Kw + BB * NN * CC;                          // total ~1.53 MB

    prep_kernel<<<264, 256, 0, stream>>>(h, WQ, WK, WV, WE, WE2,
                                         Qw, Kw, Vw, wfrag);
    attn_kernel<<<BB*NN/2, 512, 0, stream>>>(e, mask, wfrag, Qw, Kw, Vw,
                                             (float*)d_out);
}